// Round 1
// baseline (123.485 us; speedup 1.0000x reference)
//
#include <hip/hip_runtime.h>

// LIF forward: y_t = heaviside(v_{t-1}*tau + x_t - v_th), hard reset.
// x: [T=16, B*C*H*W = N] f32, y same shape. Independent per spatial element.
#define TAU 0.5f
#define V_TH 1.0f

__global__ __launch_bounds__(256) void lif_fwd_kernel(
    const float4* __restrict__ x, float4* __restrict__ y,
    int n4, int T) {
    int i = blockIdx.x * blockDim.x + threadIdx.x;
    if (i >= n4) return;

    float4 v = make_float4(0.f, 0.f, 0.f, 0.f);
    const float4* xp = x + i;
    float4* yp = y + i;

#pragma unroll
    for (int t = 0; t < 16; ++t) {
        float4 xv = *xp;
        float4 m, yv;
        // tau = 0.5: v*0.5 is exact, so fma == separate mul+add bitwise.
        m.x = v.x * TAU + xv.x;
        m.y = v.y * TAU + xv.y;
        m.z = v.z * TAU + xv.z;
        m.w = v.w * TAU + xv.w;
        yv.x = (m.x - V_TH > 0.f) ? 1.f : 0.f;
        yv.y = (m.y - V_TH > 0.f) ? 1.f : 0.f;
        yv.z = (m.z - V_TH > 0.f) ? 1.f : 0.f;
        yv.w = (m.w - V_TH > 0.f) ? 1.f : 0.f;
        v.x = (yv.x > 0.f) ? 0.f : m.x;
        v.y = (yv.y > 0.f) ? 0.f : m.y;
        v.z = (yv.z > 0.f) ? 0.f : m.z;
        v.w = (yv.w > 0.f) ? 0.f : m.w;
        *yp = yv;
        xp += n4;
        yp += n4;
    }
}

extern "C" void kernel_launch(void* const* d_in, const int* in_sizes, int n_in,
                              void* d_out, int out_size, void* d_ws, size_t ws_size,
                              hipStream_t stream) {
    const float* x = (const float*)d_in[0];
    float* y = (float*)d_out;

    const int T = 16;
    const long long total = (long long)in_sizes[0];   // 67,108,864
    const int N = (int)(total / T);                   // 4,194,304 per timestep
    const int n4 = N / 4;                             // 1,048,576 float4 lanes

    dim3 block(256);
    dim3 grid((n4 + 255) / 256);
    lif_fwd_kernel<<<grid, block, 0, stream>>>(
        (const float4*)x, (float4*)y, n4, T);
}

// Round 2
// 85.787 us; speedup vs baseline: 1.4394x; 1.4394x over previous
//
#include <hip/hip_runtime.h>

// LIF forward: y_t = heaviside(v_{t-1}*tau + x_t - v_th), hard reset.
// x: [T=16, N=4194304] f32. Independent per spatial element; scan only in T.
// Strategy: each thread owns one float4 column; issue ALL 16 timestep loads
// up front (independent addresses -> 16 outstanding loads/wave, latency
// hidden by MLP not just TLP), then walk the sequential v-chain as loads
// arrive, emitting non-temporal stores (y never re-read; keep x in L3).
#define TAU 0.5f
#define V_TH 1.0f

typedef __attribute__((ext_vector_type(4))) float f32x4;

__global__ __launch_bounds__(256) void lif_fwd_kernel(
    const f32x4* __restrict__ x, f32x4* __restrict__ y, int n4) {
    int i = blockIdx.x * blockDim.x + threadIdx.x;
    if (i >= n4) return;

    const f32x4* xp = x + i;
    f32x4* yp = y + i;

    // 16 independent loads issued back-to-back (64 VGPRs of payload).
    f32x4 xv[16];
#pragma unroll
    for (int t = 0; t < 16; ++t)
        xv[t] = xp[(size_t)t * n4];

    f32x4 v = (f32x4)0.f;
#pragma unroll
    for (int t = 0; t < 16; ++t) {
        f32x4 m, yv;
        // tau = 0.5: v*0.5 exact, so this matches the JAX reference bitwise.
        m.x = v.x * TAU + xv[t].x;
        m.y = v.y * TAU + xv[t].y;
        m.z = v.z * TAU + xv[t].z;
        m.w = v.w * TAU + xv[t].w;
        yv.x = (m.x - V_TH > 0.f) ? 1.f : 0.f;
        yv.y = (m.y - V_TH > 0.f) ? 1.f : 0.f;
        yv.z = (m.z - V_TH > 0.f) ? 1.f : 0.f;
        yv.w = (m.w - V_TH > 0.f) ? 1.f : 0.f;
        v.x = (yv.x > 0.f) ? 0.f : m.x;
        v.y = (yv.y > 0.f) ? 0.f : m.y;
        v.z = (yv.z > 0.f) ? 0.f : m.z;
        v.w = (yv.w > 0.f) ? 0.f : m.w;
        __builtin_nontemporal_store(yv, &yp[(size_t)t * n4]);
    }
}

extern "C" void kernel_launch(void* const* d_in, const int* in_sizes, int n_in,
                              void* d_out, int out_size, void* d_ws, size_t ws_size,
                              hipStream_t stream) {
    const float* x = (const float*)d_in[0];
    float* y = (float*)d_out;

    const int T = 16;
    const long long total = (long long)in_sizes[0];   // 67,108,864
    const int N = (int)(total / T);                   // 4,194,304 per timestep
    const int n4 = N / 4;                             // 1,048,576 float4 columns

    dim3 block(256);
    dim3 grid((n4 + 255) / 256);
    lif_fwd_kernel<<<grid, block, 0, stream>>>(
        (const f32x4*)x, (f32x4*)y, n4);
}